// Round 7
// baseline (171.927 us; speedup 1.0000x reference)
//
#include <hip/hip_runtime.h>
#include <math.h>

#define B_ 64
#define I_ 4096
#define P_ 8      // Din
#define N_ 10
#define D_ 16
#define ND_ 160   // N*D
#define BND_ (B_*ND_)   // 10240
#define PSTR_ 10304     // part row stride (floats): +256 B pad de-camps channels
#define EPS_ 1e-7f

#define IPB_ 8                 // i per block
#define NBLK_ (I_ / IPB_)      // 512 blocks = exactly 2 blocks/CU on 256 CUs
#define WTILE_ (N_ * P_ * D_)  // 1280 floats of W per i (global, unpadded)
#define NSTR_ 144              // padded n-stride in LDS (floats)
#define ILSTR_ (N_ * NSTR_)    // 1440 floats per i in LDS
#define XSTR_ 68               // x row stride in LDS (floats)

// tree-barrier geometry: 16 groups x 32 blocks; each counter on its own 64 B line
#define NGRP_ 16
#define GSZ_  32
#define LINEW_ 16              // uints per 64 B line
#define SLOTW_ ((NGRP_ + 1) * LINEW_)   // 17 lines per barrier slot
#define NSLOT_ 5

// DPP cross-lane value fetch on the VALU pipe (no DS traffic).
template<int CTRL>
__device__ __forceinline__ float dpp_bcast(float v) {
    int r = __builtin_amdgcn_update_dpp(0, __float_as_int(v), CTRL, 0xF, 0xF, true);
    return __int_as_float(r);
}

// ---- agent-scope (sc1) accessors: route cross-block data via the device-
// coherent point, bypassing the non-coherent per-XCD L2s. All cross-block
// data (part, Vc, cnt) moves ONLY through these. (R15/R16 lesson: NEVER use
// acq/rel on them -- buffer_inv/wbl2 cost ~16-30 us/barrier.)
__device__ __forceinline__ void agent_store_f2(float* dst, float a, float b) {
    float2 v; v.x = a; v.y = b;
    unsigned long long u; __builtin_memcpy(&u, &v, 8);
    __hip_atomic_store((unsigned long long*)dst, u,
                       __ATOMIC_RELAXED, __HIP_MEMORY_SCOPE_AGENT);
}
__device__ __forceinline__ float2 agent_load_f2(const float* src) {
    unsigned long long u = __hip_atomic_load((unsigned long long*)src,
                       __ATOMIC_RELAXED, __HIP_MEMORY_SCOPE_AGENT);
    float2 v; __builtin_memcpy(&v, &u, 8); return v;
}
__device__ __forceinline__ void agent_store_f(float* dst, float v) {
    __hip_atomic_store(dst, v, __ATOMIC_RELAXED, __HIP_MEMORY_SCOPE_AGENT);
}

// R17 tree grid barrier (proven 211->115 us), R19: SPLIT-PHASE.
// arrive = syncthreads (drains vmcnt -> all sc1 stores acked at the coherent
// point) + group fetch_add + root propagate. wait = poll + syncthreads.
// Between arrive and wait the block can do Vc-independent compute (il=0 tv).
// Monotonic epochs (any initial value / replay safe); ~20 ms timeouts break
// visibly instead of hanging.
__device__ __forceinline__ unsigned gridbar_arrive(unsigned* cnt, int slot) {
    __syncthreads();                       // all waves: vmcnt(0) drained
    unsigned epoch = 0;
    if (threadIdx.x == 0) {
        unsigned* base = cnt + slot * SLOTW_;
        const unsigned g = (unsigned)blockIdx.x & (NGRP_ - 1u);
        unsigned* gl = base + g * LINEW_;          // [0]=arrive ctr
        unsigned* rp = base + NGRP_ * LINEW_;      // root line [0]
        __builtin_amdgcn_fence(__ATOMIC_RELEASE, "workgroup");   // compiler pin
        unsigned gold = __hip_atomic_fetch_add(&gl[0], 1u,
                            __ATOMIC_RELAXED, __HIP_MEMORY_SCOPE_AGENT);
        epoch = gold / (unsigned)GSZ_;
        if ((gold % (unsigned)GSZ_) == (unsigned)GSZ_ - 1u)   // group complete
            __hip_atomic_fetch_add(&rp[0], 1u,
                __ATOMIC_RELAXED, __HIP_MEMORY_SCOPE_AGENT);
    }
    return epoch;   // meaningful in thread 0 only
}

__device__ __forceinline__ void gridbar_wait(unsigned* cnt, int slot, unsigned epoch) {
    if (threadIdx.x == 0) {
        unsigned* base = cnt + slot * SLOTW_;
        const unsigned g = (unsigned)blockIdx.x & (NGRP_ - 1u);
        unsigned* gl = base + g * LINEW_;          // [1]=go word
        unsigned* rp = base + NGRP_ * LINEW_;
        long long t0 = (long long)__builtin_amdgcn_s_memrealtime();
        if ((unsigned)blockIdx.x < (unsigned)NGRP_) {   // leader of group g
            unsigned rtgt = (epoch + 1u) * (unsigned)NGRP_;
            while (__hip_atomic_load(&rp[0], __ATOMIC_RELAXED,
                                     __HIP_MEMORY_SCOPE_AGENT) < rtgt) {
                __builtin_amdgcn_s_sleep(1);
                if ((long long)__builtin_amdgcn_s_memrealtime() - t0 > 2000000LL)
                    break;                 // ~20 ms: fail visibly, don't hang
            }
            __hip_atomic_store(&gl[1], epoch + 1u,
                __ATOMIC_RELAXED, __HIP_MEMORY_SCOPE_AGENT);
        } else {
            while (__hip_atomic_load(&gl[1], __ATOMIC_RELAXED,
                                     __HIP_MEMORY_SCOPE_AGENT) < epoch + 1u) {
                __builtin_amdgcn_s_sleep(1);
                if ((long long)__builtin_amdgcn_s_memrealtime() - t0 > 2000000LL)
                    break;
            }
        }
        __builtin_amdgcn_fence(__ATOMIC_ACQUIRE, "workgroup");   // compiler pin
    }
    __syncthreads();
}

// __launch_bounds__(256, 2) -- R2-proven AND required for barrier safety
// (512 blocks = 2/CU x 256 CU all co-resident; LDS 66KB x2 <= 160KB).
// NOT hipLaunchCooperativeKernel (R11: deadlocked under graph capture).
__global__ __launch_bounds__(256, 2)
void digitcaps_fused(const float* __restrict__ x, const float* __restrict__ W,
                     float* __restrict__ part, float* __restrict__ Vc,
                     float* __restrict__ out, unsigned* __restrict__ cnt)
{
    __shared__ float wsh[IPB_ * ILSTR_];   // 46080 B
    __shared__ float xsh[B_ * XSTR_];      // 17408 B: x[b][il*8+p], stride 68
    __shared__ float4 rsm4[32][5];         // 2560 B reduce combine
    const int t = threadIdx.x;
    const int lane = t & 63;
    const int ds  = lane & 7;              // d-pair index: d = 2ds, 2ds+1
    const int np  = (lane >> 3) & 1;       // n-parity (owns n = np+2k)
    const int bl2 = lane >> 4;             // 0..3
    const int wv  = t >> 6;                // 0..3
    const int bb  = wv * 16 + bl2 * 4;     // first of this thread's 4 b's
    const int i0  = blockIdx.x * IPB_;

    // ---- stage W[i0..i0+8) into padded LDS ONCE: 10 float4/thread ----
    {
        const float4* __restrict__ Wg = (const float4*)(W + (size_t)i0 * WTILE_);
        float4* __restrict__ Ws = (float4*)wsh;
#pragma unroll
        for (int c0 = 0; c0 < (IPB_ * WTILE_) / (4 * 256); ++c0) {  // 10
            int c  = c0 * 256 + t;
            int il = c / 320;
            int r  = c - il * 320;
            int n  = r >> 5;
            int s  = r & 31;
            Ws[il * 360 + n * 36 + s] = Wg[c];
        }
    }
    // ---- stage x[b][i0..i0+8][:] into LDS ONCE ----
    {
        const int xb = t >> 2;             // b 0..63
        const int xc = t & 3;
        const float4* __restrict__ xg = (const float4*)(x + ((size_t)xb * I_ + i0) * P_);
        float4* __restrict__ xd = (float4*)(xsh + xb * XSTR_);
#pragma unroll
        for (int q = 0; q < 4; ++q)
            xd[xc * 4 + q] = xg[xc * 4 + q];
    }
    __syncthreads();   // W + x staged

    // u_hat fragment einsum for one il (no Vc dependence -> can run while
    // waiting on the Vc barrier)
    auto compute_tv = [&](int il, float (&tv)[4][5][2]) {
        const float* __restrict__ Wb = wsh + il * ILSTR_ + np * NSTR_ + 2 * ds;
        float xr[4][P_];
#pragma unroll
        for (int j = 0; j < 4; ++j) {
            const float4* xp = (const float4*)(xsh + (bb + j) * XSTR_ + il * P_);
            float4 a0 = xp[0], a1 = xp[1];
            xr[j][0]=a0.x; xr[j][1]=a0.y; xr[j][2]=a0.z; xr[j][3]=a0.w;
            xr[j][4]=a1.x; xr[j][5]=a1.y; xr[j][6]=a1.z; xr[j][7]=a1.w;
        }
#pragma unroll
        for (int k = 0; k < 5; ++k) {
#pragma unroll
            for (int j = 0; j < 4; ++j) { tv[j][k][0] = 0.f; tv[j][k][1] = 0.f; }
#pragma unroll
            for (int p = 0; p < P_; ++p) {
                float2 w = *(const float2*)(Wb + k * 2 * NSTR_ + p * D_);
#pragma unroll
                for (int j = 0; j < 4; ++j) {
                    tv[j][k][0] = fmaf(w.x, xr[j][p], tv[j][k][0]);
                    tv[j][k][1] = fmaf(w.y, xr[j][p], tv[j][k][1]);
                }
            }
        }
    };

    float vprev = 0.f;   // owner-thread (t<20) register copy of Vc[o0+t]
    unsigned epO = 0;    // split-phase Vc-barrier epoch (thread 0)

    for (int it = 0; it < 3; ++it) {
        const bool uni = (it == 0);

        float acc[4][5][2];
#pragma unroll
        for (int j = 0; j < 4; ++j)
#pragma unroll
            for (int k = 0; k < 5; ++k) { acc[j][k][0] = 0.f; acc[j][k][1] = 0.f; }

        float vc[4][5][2];
        float tv[4][5][2];

        // il=0 einsum first; Vc wait overlaps with it (split-phase barrier)
        compute_tv(0, tv);
        if (!uni) {
            gridbar_wait(cnt, (it - 1) * 2 + 1, epO);   // Vc now visible
#pragma unroll
            for (int j = 0; j < 4; ++j)
#pragma unroll
                for (int k = 0; k < 5; ++k) {
                    float2 v = agent_load_f2(Vc + (size_t)(bb + j) * ND_
                                             + (np + 2 * k) * D_ + 2 * ds);
                    vc[j][k][0] = v.x; vc[j][k][1] = v.y;
                }
        }

#pragma unroll 1
        for (int il = 0; il < IPB_; ++il) {
            if (il > 0) compute_tv(il, tv);

            if (uni) {
#pragma unroll
                for (int j = 0; j < 4; ++j)
#pragma unroll
                    for (int k = 0; k < 5; ++k) {
                        acc[j][k][0] += tv[j][k][0];
                        acc[j][k][1] += tv[j][k][1];
                    }
            } else {
#pragma unroll
                for (int j = 0; j < 4; ++j) {
                    float e[5];
                    float m = -1e30f;
#pragma unroll
                    for (int k = 0; k < 5; ++k) {
                        float l = fmaf(tv[j][k][1], vc[j][k][1],
                                       tv[j][k][0] * vc[j][k][0]);
                        l += dpp_bcast<0xB1>(l);
                        l += dpp_bcast<0x4E>(l);
                        l += dpp_bcast<0x141>(l);   // full d-dot across 8 ds lanes
                        e[k] = l;
                        m = fmaxf(m, l);
                    }
                    m = fmaxf(m, dpp_bcast<0x140>(m));   // max over other parity
                    float se = 0.f;
#pragma unroll
                    for (int k = 0; k < 5; ++k) { e[k] = __expf(e[k] - m); se += e[k]; }
                    se += dpp_bcast<0x140>(se);
                    float inv = 1.f / se;
#pragma unroll
                    for (int k = 0; k < 5; ++k) {
                        float cn = e[k] * inv;
                        acc[j][k][0] = fmaf(cn, tv[j][k][0], acc[j][k][0]);
                        acc[j][k][1] = fmaf(cn, tv[j][k][1], acc[j][k][1]);
                    }
                }
            }
        }

        // store partials via sc1 (device-coherent), NATURAL layout + row pad
#pragma unroll
        for (int j = 0; j < 4; ++j) {
            float* __restrict__ dst = part + (size_t)blockIdx.x * PSTR_
                                      + (size_t)(bb + j) * ND_ + np * D_ + 2 * ds;
#pragma unroll
            for (int k = 0; k < 5; ++k)
                agent_store_f2(dst + k * 2 * D_, acc[j][k][0], acc[j][k][1]);
        }

        {   // part-visible barrier (nothing useful to overlap)
            unsigned epE = gridbar_arrive(cnt, it * 2);
            gridbar_wait(cnt, it * 2, epE);
        }

        // ---- R19 batched reduce: 160 threads, 5 f4-cols x 32 groups x 16
        // rows, CONSTANT trip counts. Load loop fully unrolled (32 sc1 f2
        // loads in flight) THEN accumulate -- kills R18's per-iteration
        // vmcnt(0) serialization (~8 us/iter of latency convoy).
        const int o0 = blockIdx.x * 20;
        if (t < 160) {
            const int fg = t % 5;
            const int tp = t / 5;
            const float* __restrict__ p0 = part + (size_t)(tp * 16) * PSTR_
                                           + o0 + fg * 4;
            float2 va[32];
#pragma unroll
            for (int r = 0; r < 16; ++r) {
                va[2*r]   = agent_load_f2(p0 + (size_t)r * PSTR_);
                va[2*r+1] = agent_load_f2(p0 + (size_t)r * PSTR_ + 2);
            }
            float4 s4 = {0.f, 0.f, 0.f, 0.f};
#pragma unroll
            for (int r = 0; r < 16; ++r) {
                s4.x += va[2*r].x;   s4.y += va[2*r].y;
                s4.z += va[2*r+1].x; s4.w += va[2*r+1].y;
            }
            rsm4[tp][fg] = s4;
        }
        __syncthreads();
        if (t < 20) {
            const int fg = t >> 2, c = t & 3;
            float tot = 0.f;
#pragma unroll
            for (int tp = 0; tp < 32; ++tp)
                tot += ((const float*)&rsm4[tp][fg])[c];
            tot *= uni ? 0.1f : 1.0f;
            float sq = tot * tot;
            float v = tot * (sq / ((1.f + sq) * sqrtf(sq + EPS_)));
            const int o2 = o0 + t;
            if (it == 0)      { vprev = v;   agent_store_f(Vc + o2, vprev); }
            else if (it == 1) { vprev += v;  agent_store_f(Vc + o2, vprev); }
            else              out[o2] = v;   // plain store: kernel-end writeback
        }

        if (it < 2) epO = gridbar_arrive(cnt, it * 2 + 1);   // Vc arrive only;
        // wait is deferred into the next pass (after its il=0 einsum)
    }
}

extern "C" void kernel_launch(void* const* d_in, const int* in_sizes, int n_in,
                              void* d_out, int out_size, void* d_ws, size_t ws_size,
                              hipStream_t stream)
{
    const float* x = (const float*)d_in[0];   // [64, 4096, 8] f32
    const float* W = (const float*)d_in[1];   // [4096, 10, 8, 16] f32
    float* out = (float*)d_out;               // [64, 10, 1, 16] f32

    // ws: part (512*10304 f = 21.1 MB) | Vc (10240 f) | cnt (5 slots x 17 lines)
    float* part = (float*)d_ws;
    float* Vc   = part + (size_t)NBLK_ * PSTR_;
    unsigned* cnt = (unsigned*)(Vc + BND_);

    // zero barrier counters (tree epoch math needs consistent init; poison
    // is not guaranteed zero). Graph-capturable async memset.
    hipMemsetAsync(cnt, 0, NSLOT_ * SLOTW_ * sizeof(unsigned), stream);

    digitcaps_fused<<<dim3(NBLK_), dim3(256), 0, stream>>>(x, W, part, Vc, out, cnt);
}